// Round 1
// baseline (368.434 us; speedup 1.0000x reference)
//
#include <hip/hip_runtime.h>
#include <hip/hip_bf16.h>
#include <math.h>

typedef unsigned short ushort_t;
typedef __attribute__((ext_vector_type(8))) short  bf16x8;
typedef __attribute__((ext_vector_type(4))) float  f32x4;
typedef __attribute__((ext_vector_type(4))) int    int4v;
typedef __attribute__((ext_vector_type(4))) short  s16x4;

#define MFMA16(a, b, c) __builtin_amdgcn_mfma_f32_16x16x32_bf16((a), (b), (c), 0, 0, 0)

static constexpr int BATCH = 2;
static constexpr int SEQ   = 2048;
static constexpr int DMODEL = 512;
static constexpr int NHEADS = 8;
static constexpr int DK    = 64;
static constexpr int MROWS = BATCH * SEQ;          // 4096
static constexpr int XE = MROWS * DMODEL;          // 2097152 elems
static constexpr int WE = DMODEL * DMODEL;         // 262144 elems

__device__ __forceinline__ ushort_t f2bf(float f) {
  unsigned int u = __builtin_bit_cast(unsigned int, f);
  u = (u + 0x7FFFu + ((u >> 16) & 1u)) >> 16;
  return (ushort_t)u;
}

// ---------------------------------------------------------------------------
// 1) fp32 -> bf16 conversion of x, Wq, Wk, Wv, Wo into contiguous ws region
// ---------------------------------------------------------------------------
__global__ __launch_bounds__(256) void convert_kernel(
    const float* __restrict__ x,  const float* __restrict__ wq,
    const float* __restrict__ wk, const float* __restrict__ wv,
    const float* __restrict__ wo, ushort_t* __restrict__ dst) {
  int e = (blockIdx.x * 256 + threadIdx.x) * 4;
  const float* src;
  int off;
  if (e < XE)                { src = x;  off = e; }
  else if (e < XE + WE)      { src = wq; off = e - XE; }
  else if (e < XE + 2 * WE)  { src = wk; off = e - XE - WE; }
  else if (e < XE + 3 * WE)  { src = wv; off = e - XE - 2 * WE; }
  else                       { src = wo; off = e - XE - 3 * WE; }
  float4 f = *reinterpret_cast<const float4*>(&src[off]);
  s16x4 v;
  v[0] = (short)f2bf(f.x); v[1] = (short)f2bf(f.y);
  v[2] = (short)f2bf(f.z); v[3] = (short)f2bf(f.w);
  *reinterpret_cast<s16x4*>(&dst[e]) = v;
}

// ---------------------------------------------------------------------------
// 2) bf16 GEMM:  C[m,n] = sum_k A[m,k] * Bt[n,k] + bias[n]
//    A: M x K bf16 row-major, Bt: N x K bf16 row-major (i.e. B^T form)
//    64x64 tile / workgroup, 4 waves, each wave a 16x64 stripe.
// ---------------------------------------------------------------------------
template <bool F32OUT>
__global__ __launch_bounds__(256) void gemm_bt(
    const ushort_t* __restrict__ A, const ushort_t* __restrict__ Bt,
    const float* __restrict__ bias, void* __restrict__ C,
    int M, int N, int K) {
  __shared__ ushort_t As[64][72];
  __shared__ ushort_t Bs[64][72];
  const int tid  = threadIdx.x;
  const int wave = tid >> 6, lane = tid & 63;
  const int quad = lane >> 4, l15 = lane & 15;
  const int m0 = blockIdx.y * 64, n0 = blockIdx.x * 64;

  f32x4 acc[4] = {};

  const int sr = tid >> 3;            // 0..31
  const int sc = (tid & 7) * 8;       // 0..56

  for (int k0 = 0; k0 < K; k0 += 64) {
    __syncthreads();
    *reinterpret_cast<int4v*>(&As[sr][sc]) =
        *reinterpret_cast<const int4v*>(&A[(m0 + sr) * K + k0 + sc]);
    *reinterpret_cast<int4v*>(&As[sr + 32][sc]) =
        *reinterpret_cast<const int4v*>(&A[(m0 + sr + 32) * K + k0 + sc]);
    *reinterpret_cast<int4v*>(&Bs[sr][sc]) =
        *reinterpret_cast<const int4v*>(&Bt[(n0 + sr) * K + k0 + sc]);
    *reinterpret_cast<int4v*>(&Bs[sr + 32][sc]) =
        *reinterpret_cast<const int4v*>(&Bt[(n0 + sr + 32) * K + k0 + sc]);
    __syncthreads();
#pragma unroll
    for (int s = 0; s < 2; s++) {
      bf16x8 af = *reinterpret_cast<const bf16x8*>(&As[wave * 16 + l15][s * 32 + quad * 8]);
#pragma unroll
      for (int t = 0; t < 4; t++) {
        bf16x8 bfr = *reinterpret_cast<const bf16x8*>(&Bs[t * 16 + l15][s * 32 + quad * 8]);
        acc[t] = MFMA16(af, bfr, acc[t]);
      }
    }
  }

#pragma unroll
  for (int t = 0; t < 4; t++) {
    const int col = n0 + t * 16 + l15;
    const float bv = bias[col];
#pragma unroll
    for (int rr = 0; rr < 4; rr++) {
      const int row = m0 + wave * 16 + quad * 4 + rr;
      const float v = acc[t][rr] + bv;
      if (F32OUT) reinterpret_cast<float*>(C)[row * N + col] = v;
      else        reinterpret_cast<ushort_t*>(C)[row * N + col] = f2bf(v);
    }
  }
}

// ---------------------------------------------------------------------------
// 3) Fused flash attention with additive tree biases.
//    Grid: (qblocks=32, heads=8, batch=2); 256 thr = 4 waves; each wave owns
//    a 16-query stripe of the 64-query block. K-blocks of 64 iterated online.
// ---------------------------------------------------------------------------
__global__ __launch_bounds__(256) void attn_kernel(
    const ushort_t* __restrict__ Qb, const ushort_t* __restrict__ Kb,
    const ushort_t* __restrict__ Vb,
    const float* __restrict__ Dm, const float* __restrict__ Am,
    const float* __restrict__ wd, const float* __restrict__ wa,
    ushort_t* __restrict__ AO) {
  const int qb = blockIdx.x, h = blockIdx.y, b = blockIdx.z;
  const int tid = threadIdx.x;
  const int wave = tid >> 6, lane = tid & 63;
  const int quad = lane >> 4, l15 = lane & 15;
  const int q0 = qb * 64;
  const float scale = 0.125f;
  const float wdh = wd[h], wah = wa[h];

  __shared__ ushort_t Ks[64][72];
  __shared__ ushort_t Vts[64][72];
  __shared__ ushort_t Ps[4][16][72];

  // Q fragments for this wave's 16-query stripe (kept in registers)
  const int qrow = q0 + wave * 16 + l15;
  bf16x8 qf[2];
#pragma unroll
  for (int s = 0; s < 2; s++)
    qf[s] = *reinterpret_cast<const bf16x8*>(
        &Qb[(b * SEQ + qrow) * DMODEL + h * DK + s * 32 + quad * 8]);

  float m_run[4], l_run[4];
  f32x4 o[4] = {};
#pragma unroll
  for (int rr = 0; rr < 4; rr++) { m_run[rr] = -INFINITY; l_run[rr] = 0.f; }

  const int sr = tid >> 3;       // 0..31
  const int sc = (tid & 7) * 8;  // 0..56
  const int biasRowBase = b * SEQ;  // rows of D/A for this batch

  for (int kb = 0; kb < 32; kb++) {
    const int k0 = kb * 64;
    __syncthreads();
    // stage K tile (row-major) and V tile (transposed) into LDS
    *reinterpret_cast<int4v*>(&Ks[sr][sc]) =
        *reinterpret_cast<const int4v*>(&Kb[(b * SEQ + k0 + sr) * DMODEL + h * DK + sc]);
    *reinterpret_cast<int4v*>(&Ks[sr + 32][sc]) =
        *reinterpret_cast<const int4v*>(&Kb[(b * SEQ + k0 + sr + 32) * DMODEL + h * DK + sc]);
    bf16x8 v0 = *reinterpret_cast<const bf16x8*>(&Vb[(b * SEQ + k0 + sr) * DMODEL + h * DK + sc]);
    bf16x8 v1 = *reinterpret_cast<const bf16x8*>(&Vb[(b * SEQ + k0 + sr + 32) * DMODEL + h * DK + sc]);
#pragma unroll
    for (int j = 0; j < 8; j++) {
      Vts[sc + j][sr]      = (ushort_t)v0[j];
      Vts[sc + j][sr + 32] = (ushort_t)v1[j];
    }
    __syncthreads();

    // S = (Q K^T) * scale + wd*D + wa*A   (16q x 64k stripe per wave)
    f32x4 sacc[4];
#pragma unroll
    for (int t = 0; t < 4; t++) {
      bf16x8 kf0 = *reinterpret_cast<const bf16x8*>(&Ks[t * 16 + l15][quad * 8]);
      bf16x8 kf1 = *reinterpret_cast<const bf16x8*>(&Ks[t * 16 + l15][32 + quad * 8]);
      f32x4 z = {};
      z = MFMA16(qf[0], kf0, z);
      sacc[t] = MFMA16(qf[1], kf1, z);
    }

    float sv[4][4];
    float mx[4] = {-INFINITY, -INFINITY, -INFINITY, -INFINITY};
#pragma unroll
    for (int t = 0; t < 4; t++) {
      const int kk = k0 + t * 16 + l15;
#pragma unroll
      for (int rr = 0; rr < 4; rr++) {
        const int qg = q0 + wave * 16 + quad * 4 + rr;
        const int idx = (biasRowBase + qg) * SEQ + kk;
        float s = sacc[t][rr] * scale + wdh * Dm[idx] + wah * Am[idx];
        sv[t][rr] = s;
        mx[rr] = fmaxf(mx[rr], s);
      }
    }
    // row-max across the 16 lanes of each quad
#pragma unroll
    for (int rr = 0; rr < 4; rr++) {
      float m = mx[rr];
#pragma unroll
      for (int off = 1; off < 16; off <<= 1) m = fmaxf(m, __shfl_xor(m, off, 64));
      mx[rr] = m;
    }
    float alpha[4], rs[4];
#pragma unroll
    for (int rr = 0; rr < 4; rr++) {
      const float mn = fmaxf(m_run[rr], mx[rr]);
      alpha[rr] = __expf(m_run[rr] - mn);
      m_run[rr] = mn;
      rs[rr] = 0.f;
    }
#pragma unroll
    for (int t = 0; t < 4; t++) {
#pragma unroll
      for (int rr = 0; rr < 4; rr++) {
        const float p = __expf(sv[t][rr] - m_run[rr]);
        rs[rr] += p;
        Ps[wave][quad * 4 + rr][t * 16 + l15] = f2bf(p);
      }
    }
#pragma unroll
    for (int rr = 0; rr < 4; rr++) {
      float s = rs[rr];
#pragma unroll
      for (int off = 1; off < 16; off <<= 1) s += __shfl_xor(s, off, 64);
      l_run[rr] = l_run[rr] * alpha[rr] + s;
    }
#pragma unroll
    for (int dt = 0; dt < 4; dt++)
#pragma unroll
      for (int rr = 0; rr < 4; rr++) o[dt][rr] *= alpha[rr];

    __syncthreads();  // make P LDS writes visible / ordered before frag reads

    // O += P @ V
#pragma unroll
    for (int s2 = 0; s2 < 2; s2++) {
      bf16x8 pf = *reinterpret_cast<const bf16x8*>(&Ps[wave][l15][s2 * 32 + quad * 8]);
#pragma unroll
      for (int dt = 0; dt < 4; dt++) {
        bf16x8 vf = *reinterpret_cast<const bf16x8*>(&Vts[dt * 16 + l15][s2 * 32 + quad * 8]);
        o[dt] = MFMA16(pf, vf, o[dt]);
      }
    }
  }

  // epilogue: normalize and store bf16
  float inv_l[4];
#pragma unroll
  for (int rr = 0; rr < 4; rr++) inv_l[rr] = 1.f / l_run[rr];
#pragma unroll
  for (int dt = 0; dt < 4; dt++) {
#pragma unroll
    for (int rr = 0; rr < 4; rr++) {
      const int row = b * SEQ + q0 + wave * 16 + quad * 4 + rr;
      const int col = h * DK + dt * 16 + l15;
      AO[row * DMODEL + col] = f2bf(o[dt][rr] * inv_l[rr]);
    }
  }
}

// ---------------------------------------------------------------------------
extern "C" void kernel_launch(void* const* d_in, const int* in_sizes, int n_in,
                              void* d_out, int out_size, void* d_ws, size_t ws_size,
                              hipStream_t stream) {
  const float* x  = (const float*)d_in[0];
  const float* Dm = (const float*)d_in[1];
  const float* Am = (const float*)d_in[2];
  const float* Wq = (const float*)d_in[3];
  const float* bq = (const float*)d_in[4];
  const float* Wk = (const float*)d_in[5];
  const float* bk = (const float*)d_in[6];
  const float* Wv = (const float*)d_in[7];
  const float* bv = (const float*)d_in[8];
  const float* Wo = (const float*)d_in[9];
  const float* bo = (const float*)d_in[10];
  const float* wd = (const float*)d_in[11];
  const float* wa = (const float*)d_in[12];

  char* ws = (char*)d_ws;
  // bf16 workspace layout (bytes)
  ushort_t* xb  = (ushort_t*)(ws);                       // 4 MB  (x)
  ushort_t* wqb = (ushort_t*)(ws + (size_t)XE * 2);      // 512 KB each
  ushort_t* wkb = (ushort_t*)(ws + (size_t)(XE + WE) * 2);
  ushort_t* wvb = (ushort_t*)(ws + (size_t)(XE + 2 * WE) * 2);
  ushort_t* wob = (ushort_t*)(ws + (size_t)(XE + 3 * WE) * 2);
  ushort_t* Qb  = (ushort_t*)(ws + (size_t)(XE + 4 * WE) * 2);
  ushort_t* Kb  = (ushort_t*)(ws + (size_t)(2 * XE + 4 * WE) * 2);
  ushort_t* Vb  = (ushort_t*)(ws + (size_t)(3 * XE + 4 * WE) * 2);
  ushort_t* AO  = (ushort_t*)(ws + (size_t)(4 * XE + 4 * WE) * 2);

  // 1) convert inputs to bf16
  const int conv_elems = XE + 4 * WE;
  convert_kernel<<<conv_elems / (256 * 4), 256, 0, stream>>>(x, Wq, Wk, Wv, Wo, xb);

  // 2) projections
  dim3 ggrid(DMODEL / 64, MROWS / 64);
  gemm_bt<false><<<ggrid, 256, 0, stream>>>(xb, wqb, bq, Qb, MROWS, DMODEL, DMODEL);
  gemm_bt<false><<<ggrid, 256, 0, stream>>>(xb, wkb, bk, Kb, MROWS, DMODEL, DMODEL);
  gemm_bt<false><<<ggrid, 256, 0, stream>>>(xb, wvb, bv, Vb, MROWS, DMODEL, DMODEL);

  // 3) fused attention
  dim3 agrid(SEQ / 64, NHEADS, BATCH);
  attn_kernel<<<agrid, 256, 0, stream>>>(Qb, Kb, Vb, Dm, Am, wd, wa, AO);

  // 4) output projection (fp32 out)
  gemm_bt<true><<<ggrid, 256, 0, stream>>>(AO, wob, bo, (float*)d_out, MROWS, DMODEL, DMODEL);
}

// Round 2
// 267.683 us; speedup vs baseline: 1.3764x; 1.3764x over previous
//
#include <hip/hip_runtime.h>
#include <hip/hip_bf16.h>
#include <math.h>

typedef unsigned short ushort_t;
typedef unsigned int   uint_t;
typedef __attribute__((ext_vector_type(8))) short  bf16x8;
typedef __attribute__((ext_vector_type(4))) float  f32x4;
typedef __attribute__((ext_vector_type(4))) int    int4v;
typedef __attribute__((ext_vector_type(4))) short  s16x4;

#define MFMA16(a, b, c) __builtin_amdgcn_mfma_f32_16x16x32_bf16((a), (b), (c), 0, 0, 0)

static constexpr int BATCH = 2;
static constexpr int SEQ   = 2048;
static constexpr int DMODEL = 512;
static constexpr int NHEADS = 8;
static constexpr int DK    = 64;
static constexpr int MROWS = BATCH * SEQ;          // 4096
static constexpr int XE = MROWS * DMODEL;          // 2097152 elems
static constexpr int WE = DMODEL * DMODEL;         // 262144 elems
static constexpr int NSPLIT = 4;                   // split-K factor for attention
static constexpr int KB_PER = (SEQ / 64) / NSPLIT; // 8 k-blocks per split

__device__ __forceinline__ ushort_t f2bf(float f) {
  unsigned int u = __builtin_bit_cast(unsigned int, f);
  u = (u + 0x7FFFu + ((u >> 16) & 1u)) >> 16;
  return (ushort_t)u;
}

// ---------------------------------------------------------------------------
// 1a) fp32 -> bf16 conversion of x, Wq, Wk, Wv, Wo
// ---------------------------------------------------------------------------
__global__ __launch_bounds__(256) void convert_kernel(
    const float* __restrict__ x,  const float* __restrict__ wq,
    const float* __restrict__ wk, const float* __restrict__ wv,
    const float* __restrict__ wo, ushort_t* __restrict__ dst) {
  int e = (blockIdx.x * 256 + threadIdx.x) * 4;
  const float* src;
  int off;
  if (e < XE)                { src = x;  off = e; }
  else if (e < XE + WE)      { src = wq; off = e - XE; }
  else if (e < XE + 2 * WE)  { src = wk; off = e - XE - WE; }
  else if (e < XE + 3 * WE)  { src = wv; off = e - XE - 2 * WE; }
  else                       { src = wo; off = e - XE - 3 * WE; }
  float4 f = *reinterpret_cast<const float4*>(&src[off]);
  s16x4 v;
  v[0] = (short)f2bf(f.x); v[1] = (short)f2bf(f.y);
  v[2] = (short)f2bf(f.z); v[3] = (short)f2bf(f.w);
  *reinterpret_cast<s16x4*>(&dst[e]) = v;
}

// ---------------------------------------------------------------------------
// 1b) pack D,A (fp32) -> interleaved bf16 pairs: lo16 = D, hi16 = A
// ---------------------------------------------------------------------------
__global__ __launch_bounds__(256) void pack_da_kernel(
    const float* __restrict__ Dm, const float* __restrict__ Am,
    uint_t* __restrict__ out) {
  int e = (blockIdx.x * 256 + threadIdx.x) * 4;
  float4 d = *reinterpret_cast<const float4*>(&Dm[e]);
  float4 a = *reinterpret_cast<const float4*>(&Am[e]);
  int4v v;
  v[0] = (int)((uint_t)f2bf(d.x) | ((uint_t)f2bf(a.x) << 16));
  v[1] = (int)((uint_t)f2bf(d.y) | ((uint_t)f2bf(a.y) << 16));
  v[2] = (int)((uint_t)f2bf(d.z) | ((uint_t)f2bf(a.z) << 16));
  v[3] = (int)((uint_t)f2bf(d.w) | ((uint_t)f2bf(a.w) << 16));
  *reinterpret_cast<int4v*>(&out[e]) = v;
}

// ---------------------------------------------------------------------------
// 2) bf16 GEMM:  C[m,n] = sum_k A[m,k] * Bt[n,k] + bias[n]
// ---------------------------------------------------------------------------
template <bool F32OUT>
__global__ __launch_bounds__(256) void gemm_bt(
    const ushort_t* __restrict__ A, const ushort_t* __restrict__ Bt,
    const float* __restrict__ bias, void* __restrict__ C,
    int M, int N, int K) {
  __shared__ ushort_t As[64][72];
  __shared__ ushort_t Bs[64][72];
  const int tid  = threadIdx.x;
  const int wave = tid >> 6, lane = tid & 63;
  const int quad = lane >> 4, l15 = lane & 15;
  const int m0 = blockIdx.y * 64, n0 = blockIdx.x * 64;

  f32x4 acc[4] = {};

  const int sr = tid >> 3;            // 0..31
  const int sc = (tid & 7) * 8;       // 0..56

  for (int k0 = 0; k0 < K; k0 += 64) {
    __syncthreads();
    *reinterpret_cast<int4v*>(&As[sr][sc]) =
        *reinterpret_cast<const int4v*>(&A[(m0 + sr) * K + k0 + sc]);
    *reinterpret_cast<int4v*>(&As[sr + 32][sc]) =
        *reinterpret_cast<const int4v*>(&A[(m0 + sr + 32) * K + k0 + sc]);
    *reinterpret_cast<int4v*>(&Bs[sr][sc]) =
        *reinterpret_cast<const int4v*>(&Bt[(n0 + sr) * K + k0 + sc]);
    *reinterpret_cast<int4v*>(&Bs[sr + 32][sc]) =
        *reinterpret_cast<const int4v*>(&Bt[(n0 + sr + 32) * K + k0 + sc]);
    __syncthreads();
#pragma unroll
    for (int s = 0; s < 2; s++) {
      bf16x8 af = *reinterpret_cast<const bf16x8*>(&As[wave * 16 + l15][s * 32 + quad * 8]);
#pragma unroll
      for (int t = 0; t < 4; t++) {
        bf16x8 bfr = *reinterpret_cast<const bf16x8*>(&Bs[t * 16 + l15][s * 32 + quad * 8]);
        acc[t] = MFMA16(af, bfr, acc[t]);
      }
    }
  }

#pragma unroll
  for (int t = 0; t < 4; t++) {
    const int col = n0 + t * 16 + l15;
    const float bv = bias[col];
#pragma unroll
    for (int rr = 0; rr < 4; rr++) {
      const int row = m0 + wave * 16 + quad * 4 + rr;
      const float v = acc[t][rr] + bv;
      if (F32OUT) reinterpret_cast<float*>(C)[row * N + col] = v;
      else        reinterpret_cast<ushort_t*>(C)[row * N + col] = f2bf(v);
    }
  }
}

// ---------------------------------------------------------------------------
// 3) Fused flash attention with additive tree biases, split-K over k-blocks.
//    Grid: (qblocks=32, heads=8, batch*NSPLIT); 256 thr = 4 waves.
//    Each WG covers KB_PER k-blocks of 64 and writes fp32 partial O, m, l.
// ---------------------------------------------------------------------------
__global__ __launch_bounds__(256) void attn_kernel(
    const ushort_t* __restrict__ Qb, const ushort_t* __restrict__ Kb,
    const ushort_t* __restrict__ Vb, const uint_t* __restrict__ DA,
    const float* __restrict__ wd, const float* __restrict__ wa,
    float* __restrict__ Opart, float* __restrict__ Mp, float* __restrict__ Lp) {
  const int qb = blockIdx.x, h = blockIdx.y;
  const int b = blockIdx.z / NSPLIT, split = blockIdx.z % NSPLIT;
  const int tid = threadIdx.x;
  const int wave = tid >> 6, lane = tid & 63;
  const int quad = lane >> 4, l15 = lane & 15;
  const int q0 = qb * 64;
  const float scale = 0.125f;
  const float wdh = wd[h], wah = wa[h];

  __shared__ ushort_t Ks[64][72];
  __shared__ ushort_t Vts[64][64];   // V^T tile, XOR-swizzled column blocks
  __shared__ ushort_t Ps[4][16][72];

  // Q fragments for this wave's 16-query stripe
  const int qrow = q0 + wave * 16 + l15;
  bf16x8 qf[2];
#pragma unroll
  for (int s = 0; s < 2; s++)
    qf[s] = *reinterpret_cast<const bf16x8*>(
        &Qb[(b * SEQ + qrow) * DMODEL + h * DK + s * 32 + quad * 8]);

  float m_run[4], l_run[4];
  f32x4 o[4] = {};
#pragma unroll
  for (int rr = 0; rr < 4; rr++) { m_run[rr] = -INFINITY; l_run[rr] = 0.f; }

  const int sr = tid >> 3;       // 0..31
  const int sc = (tid & 7) * 8;  // 0..56
  const int c7 = tid & 7;        // = (sc+j)>>3 for j in 0..7
  const uint_t* DArow = DA + (size_t)b * SEQ * SEQ;

  for (int kbi = 0; kbi < KB_PER; kbi++) {
    const int k0 = (split * KB_PER + kbi) * 64;
    __syncthreads();
    // stage K tile (row-major, padded) and V tile (transposed, swizzled)
    *reinterpret_cast<int4v*>(&Ks[sr][sc]) =
        *reinterpret_cast<const int4v*>(&Kb[(b * SEQ + k0 + sr) * DMODEL + h * DK + sc]);
    *reinterpret_cast<int4v*>(&Ks[sr + 32][sc]) =
        *reinterpret_cast<const int4v*>(&Kb[(b * SEQ + k0 + sr + 32) * DMODEL + h * DK + sc]);
    bf16x8 v0 = *reinterpret_cast<const bf16x8*>(&Vb[(b * SEQ + k0 + sr) * DMODEL + h * DK + sc]);
    bf16x8 v1 = *reinterpret_cast<const bf16x8*>(&Vb[(b * SEQ + k0 + sr + 32) * DMODEL + h * DK + sc]);
    // element (d=sc+j, k) goes to col (k&7) + 8*((k>>3) ^ (d>>3)); d>>3 == c7
    const int col0 = (sr & 7) + 8 * ((sr >> 3) ^ c7);
    const int col1 = (sr & 7) + 8 * (((sr >> 3) + 4) ^ c7);
#pragma unroll
    for (int j = 0; j < 8; j++) {
      Vts[sc + j][col0] = (ushort_t)v0[j];
      Vts[sc + j][col1] = (ushort_t)v1[j];
    }
    __syncthreads();

    // issue bias loads early (overlap with QK^T MFMA)
    uint_t da[4][4];
#pragma unroll
    for (int t = 0; t < 4; t++) {
      const int kk = k0 + t * 16 + l15;
#pragma unroll
      for (int rr = 0; rr < 4; rr++) {
        const int qg = q0 + wave * 16 + quad * 4 + rr;
        da[t][rr] = DArow[(size_t)qg * SEQ + kk];
      }
    }

    // S = (Q K^T) * scale + wd*D + wa*A
    f32x4 sacc[4];
#pragma unroll
    for (int t = 0; t < 4; t++) {
      bf16x8 kf0 = *reinterpret_cast<const bf16x8*>(&Ks[t * 16 + l15][quad * 8]);
      bf16x8 kf1 = *reinterpret_cast<const bf16x8*>(&Ks[t * 16 + l15][32 + quad * 8]);
      f32x4 z = {};
      z = MFMA16(qf[0], kf0, z);
      sacc[t] = MFMA16(qf[1], kf1, z);
    }

    float sv[4][4];
    float mx[4] = {-INFINITY, -INFINITY, -INFINITY, -INFINITY};
#pragma unroll
    for (int t = 0; t < 4; t++) {
#pragma unroll
      for (int rr = 0; rr < 4; rr++) {
        const float fd = __builtin_bit_cast(float, da[t][rr] << 16);
        const float fa = __builtin_bit_cast(float, da[t][rr] & 0xFFFF0000u);
        float s = fmaf(wdh, fd, fmaf(wah, fa, sacc[t][rr] * scale));
        sv[t][rr] = s;
        mx[rr] = fmaxf(mx[rr], s);
      }
    }
    // row-max across the 16 lanes of each quad
#pragma unroll
    for (int rr = 0; rr < 4; rr++) {
      float m = mx[rr];
#pragma unroll
      for (int off = 1; off < 16; off <<= 1) m = fmaxf(m, __shfl_xor(m, off, 64));
      mx[rr] = m;
    }
    float alpha[4], rs[4];
#pragma unroll
    for (int rr = 0; rr < 4; rr++) {
      const float mn = fmaxf(m_run[rr], mx[rr]);
      alpha[rr] = __expf(m_run[rr] - mn);
      m_run[rr] = mn;
      rs[rr] = 0.f;
    }
#pragma unroll
    for (int t = 0; t < 4; t++) {
#pragma unroll
      for (int rr = 0; rr < 4; rr++) {
        const float p = __expf(sv[t][rr] - m_run[rr]);
        rs[rr] += p;
        Ps[wave][quad * 4 + rr][t * 16 + l15] = f2bf(p);
      }
    }
#pragma unroll
    for (int rr = 0; rr < 4; rr++) {
      float s = rs[rr];
#pragma unroll
      for (int off = 1; off < 16; off <<= 1) s += __shfl_xor(s, off, 64);
      l_run[rr] = l_run[rr] * alpha[rr] + s;
    }
#pragma unroll
    for (int dt = 0; dt < 4; dt++)
#pragma unroll
      for (int rr = 0; rr < 4; rr++) o[dt][rr] *= alpha[rr];

    // Ps is wave-private: wave-local LDS drain is enough (no barrier)
    asm volatile("s_waitcnt lgkmcnt(0)" ::: "memory");

    // O += P @ V
#pragma unroll
    for (int s2 = 0; s2 < 2; s2++) {
      bf16x8 pf = *reinterpret_cast<const bf16x8*>(&Ps[wave][l15][s2 * 32 + quad * 8]);
#pragma unroll
      for (int dt = 0; dt < 4; dt++) {
        const int vrow = dt * 16 + l15;
        const int vcb = (s2 * 4 + quad) ^ (vrow >> 3);
        bf16x8 vf = *reinterpret_cast<const bf16x8*>(&Vts[vrow][vcb * 8]);
        o[dt] = MFMA16(pf, vf, o[dt]);
      }
    }
  }

  // epilogue: write fp32 partials (un-normalized) + m, l
  const int pidx = (((b * NHEADS + h) * 32 + qb) * NSPLIT + split);
  float* op = Opart + (size_t)pidx * 4096;
#pragma unroll
  for (int dt = 0; dt < 4; dt++) {
#pragma unroll
    for (int rr = 0; rr < 4; rr++) {
      const int row = wave * 16 + quad * 4 + rr;
      op[row * 64 + dt * 16 + l15] = o[dt][rr];
    }
  }
  if (l15 == 0) {
#pragma unroll
    for (int rr = 0; rr < 4; rr++) {
      const int row = wave * 16 + quad * 4 + rr;
      Mp[(size_t)pidx * 64 + row] = m_run[rr];
      Lp[(size_t)pidx * 64 + row] = l_run[rr];
    }
  }
}

// ---------------------------------------------------------------------------
// 3b) split-K combine: O = sum_s O_s * exp(m_s - M) / sum_s l_s * exp(m_s - M)
// ---------------------------------------------------------------------------
__global__ __launch_bounds__(256) void combine_kernel(
    const float* __restrict__ Opart, const float* __restrict__ Mp,
    const float* __restrict__ Lp, ushort_t* __restrict__ AO) {
  const int qb = blockIdx.x, h = blockIdx.y, b = blockIdx.z;
  const int tid = threadIdx.x;
  const int lane = tid & 63, wq = tid >> 6;
  const int pidx0 = ((b * NHEADS + h) * 32 + qb) * NSPLIT;

  for (int r = 0; r < 16; r++) {
    const int q = wq * 16 + r;
    float m[NSPLIT], l[NSPLIT];
    float M = -INFINITY;
#pragma unroll
    for (int s = 0; s < NSPLIT; s++) {
      m[s] = Mp[(size_t)(pidx0 + s) * 64 + q];
      l[s] = Lp[(size_t)(pidx0 + s) * 64 + q];
      M = fmaxf(M, m[s]);
    }
    float L = 0.f, acc = 0.f;
#pragma unroll
    for (int s = 0; s < NSPLIT; s++) {
      const float w = __expf(m[s] - M);
      L += l[s] * w;
      acc += Opart[(size_t)(pidx0 + s) * 4096 + q * 64 + lane] * w;
    }
    const int row = b * SEQ + qb * 64 + q;
    AO[(size_t)row * DMODEL + h * DK + lane] = f2bf(acc / L);
  }
}

// ---------------------------------------------------------------------------
extern "C" void kernel_launch(void* const* d_in, const int* in_sizes, int n_in,
                              void* d_out, int out_size, void* d_ws, size_t ws_size,
                              hipStream_t stream) {
  const float* x  = (const float*)d_in[0];
  const float* Dm = (const float*)d_in[1];
  const float* Am = (const float*)d_in[2];
  const float* Wq = (const float*)d_in[3];
  const float* bq = (const float*)d_in[4];
  const float* Wk = (const float*)d_in[5];
  const float* bk = (const float*)d_in[6];
  const float* Wv = (const float*)d_in[7];
  const float* bv = (const float*)d_in[8];
  const float* Wo = (const float*)d_in[9];
  const float* bo = (const float*)d_in[10];
  const float* wd = (const float*)d_in[11];
  const float* wa = (const float*)d_in[12];

  char* ws = (char*)d_ws;
  ushort_t* xb  = (ushort_t*)(ws);
  ushort_t* wqb = (ushort_t*)(ws + (size_t)XE * 2);
  ushort_t* wkb = (ushort_t*)(ws + (size_t)(XE + WE) * 2);
  ushort_t* wvb = (ushort_t*)(ws + (size_t)(XE + 2 * WE) * 2);
  ushort_t* wob = (ushort_t*)(ws + (size_t)(XE + 3 * WE) * 2);
  ushort_t* Qb  = (ushort_t*)(ws + (size_t)(XE + 4 * WE) * 2);
  ushort_t* Kb  = (ushort_t*)(ws + (size_t)(2 * XE + 4 * WE) * 2);
  ushort_t* Vb  = (ushort_t*)(ws + (size_t)(3 * XE + 4 * WE) * 2);
  ushort_t* AO  = (ushort_t*)(ws + (size_t)(4 * XE + 4 * WE) * 2);
  size_t off = (size_t)(5 * XE + 4 * WE) * 2;
  uint_t* DAb   = (uint_t*)(ws + off);                 off += (size_t)BATCH * SEQ * SEQ * 4;
  float*  Opart = (float*)(ws + off);                  off += (size_t)512 * NSPLIT * 4096 * 4;
  float*  Mpart = (float*)(ws + off);                  off += (size_t)512 * NSPLIT * 64 * 4;
  float*  Lpart = (float*)(ws + off);

  // 1) convert inputs to bf16; pack D/A
  const int conv_elems = XE + 4 * WE;
  convert_kernel<<<conv_elems / 1024, 256, 0, stream>>>(x, Wq, Wk, Wv, Wo, xb);
  pack_da_kernel<<<(BATCH * SEQ * SEQ) / 1024, 256, 0, stream>>>(Dm, Am, DAb);

  // 2) projections
  dim3 ggrid(DMODEL / 64, MROWS / 64);
  gemm_bt<false><<<ggrid, 256, 0, stream>>>(xb, wqb, bq, Qb, MROWS, DMODEL, DMODEL);
  gemm_bt<false><<<ggrid, 256, 0, stream>>>(xb, wkb, bk, Kb, MROWS, DMODEL, DMODEL);
  gemm_bt<false><<<ggrid, 256, 0, stream>>>(xb, wvb, bv, Vb, MROWS, DMODEL, DMODEL);

  // 3) fused attention (split-K) + combine
  dim3 agrid(SEQ / 64, NHEADS, BATCH * NSPLIT);
  attn_kernel<<<agrid, 256, 0, stream>>>(Qb, Kb, Vb, DAb, wd, wa, Opart, Mpart, Lpart);
  dim3 cgrid(SEQ / 64, NHEADS, BATCH);
  combine_kernel<<<cgrid, 256, 0, stream>>>(Opart, Mpart, Lpart, AO);

  // 4) output projection (fp32 out)
  gemm_bt<true><<<ggrid, 256, 0, stream>>>(AO, wob, bo, (float*)d_out, MROWS, DMODEL, DMODEL);
}

// Round 3
// 239.396 us; speedup vs baseline: 1.5390x; 1.1182x over previous
//
#include <hip/hip_runtime.h>
#include <hip/hip_bf16.h>
#include <math.h>

typedef unsigned short ushort_t;
typedef unsigned int   uint_t;
typedef __attribute__((ext_vector_type(8))) short  bf16x8;
typedef __attribute__((ext_vector_type(4))) float  f32x4;
typedef __attribute__((ext_vector_type(4))) int    int4v;
typedef __attribute__((ext_vector_type(4))) short  s16x4;

#define MFMA16(a, b, c) __builtin_amdgcn_mfma_f32_16x16x32_bf16((a), (b), (c), 0, 0, 0)

static constexpr int BATCH = 2;
static constexpr int SEQ   = 2048;
static constexpr int DMODEL = 512;
static constexpr int NHEADS = 8;
static constexpr int DK    = 64;
static constexpr int MROWS = BATCH * SEQ;          // 4096
static constexpr int XE = MROWS * DMODEL;          // 2097152 elems
static constexpr int WE = DMODEL * DMODEL;         // 262144 elems
static constexpr int NQKV = 3 * DMODEL;            // 1536 fused-projection cols
static constexpr int NSPLIT = 4;                   // split-K factor for attention
static constexpr int KB_PER = (SEQ / 64) / NSPLIT; // 8 k-blocks per split

__device__ __forceinline__ ushort_t f2bf(float f) {
  unsigned int u = __builtin_bit_cast(unsigned int, f);
  u = (u + 0x7FFFu + ((u >> 16) & 1u)) >> 16;
  return (ushort_t)u;
}

// async 16B/lane global -> LDS (lands at lds_base + lane*16)
__device__ __forceinline__ void async16(const ushort_t* g, ushort_t* l) {
  __builtin_amdgcn_global_load_lds(
      (const __attribute__((address_space(1))) unsigned int*)g,
      (__attribute__((address_space(3))) unsigned int*)l, 16, 0, 0);
}

// ---------------------------------------------------------------------------
// 1a) fp32 -> bf16 conversion of x, Wq, Wk, Wv, Wo; last block concats biases
// ---------------------------------------------------------------------------
__global__ __launch_bounds__(256) void convert_kernel(
    const float* __restrict__ x,  const float* __restrict__ wq,
    const float* __restrict__ wk, const float* __restrict__ wv,
    const float* __restrict__ wo,
    const float* __restrict__ bq, const float* __restrict__ bk,
    const float* __restrict__ bv,
    ushort_t* __restrict__ dst, float* __restrict__ bqkv) {
  const int bid = blockIdx.x;
  if (bid == (XE + 4 * WE) / 1024) {  // bias-concat block
    for (int i = threadIdx.x; i < NQKV; i += 256) {
      bqkv[i] = (i < 512) ? bq[i] : (i < 1024) ? bk[i - 512] : bv[i - 1024];
    }
    return;
  }
  int e = (bid * 256 + threadIdx.x) * 4;
  const float* src;
  int off;
  if (e < XE)                { src = x;  off = e; }
  else if (e < XE + WE)      { src = wq; off = e - XE; }
  else if (e < XE + 2 * WE)  { src = wk; off = e - XE - WE; }
  else if (e < XE + 3 * WE)  { src = wv; off = e - XE - 2 * WE; }
  else                       { src = wo; off = e - XE - 3 * WE; }
  float4 f = *reinterpret_cast<const float4*>(&src[off]);
  s16x4 v;
  v[0] = (short)f2bf(f.x); v[1] = (short)f2bf(f.y);
  v[2] = (short)f2bf(f.z); v[3] = (short)f2bf(f.w);
  *reinterpret_cast<s16x4*>(&dst[e]) = v;
}

// ---------------------------------------------------------------------------
// 1b) pack D,A (fp32) -> interleaved bf16 pairs: lo16 = D, hi16 = A
// ---------------------------------------------------------------------------
__global__ __launch_bounds__(256) void pack_da_kernel(
    const float* __restrict__ Dm, const float* __restrict__ Am,
    uint_t* __restrict__ out) {
  int e = (blockIdx.x * 256 + threadIdx.x) * 4;
  float4 d = *reinterpret_cast<const float4*>(&Dm[e]);
  float4 a = *reinterpret_cast<const float4*>(&Am[e]);
  int4v v;
  v[0] = (int)((uint_t)f2bf(d.x) | ((uint_t)f2bf(a.x) << 16));
  v[1] = (int)((uint_t)f2bf(d.y) | ((uint_t)f2bf(a.y) << 16));
  v[2] = (int)((uint_t)f2bf(d.z) | ((uint_t)f2bf(a.z) << 16));
  v[3] = (int)((uint_t)f2bf(d.w) | ((uint_t)f2bf(a.w) << 16));
  *reinterpret_cast<int4v*>(&out[e]) = v;
}

// ---------------------------------------------------------------------------
// 2) bf16 GEMM:  C[m,n] = sum_k A[m,k] * Bt[n,k] + bias[n]
//    64x64 tile / WG, async global_load_lds staging, XOR-swizzled LDS.
//    LDS[r][slot*8+j] holds global col block (slot ^ (r&7)) of the k-tile.
// ---------------------------------------------------------------------------
template <bool F32OUT>
__global__ __launch_bounds__(256) void gemm_bt(
    const ushort_t* __restrict__ A, const ushort_t* __restrict__ Bt,
    const float* __restrict__ bias, void* __restrict__ C,
    int N, int K) {
  __shared__ ushort_t As[64][64];
  __shared__ ushort_t Bs[64][64];
  const int tid  = threadIdx.x;
  const int wave = tid >> 6, lane = tid & 63;
  const int quad = lane >> 4, l15 = lane & 15;
  const int m0 = blockIdx.y * 64, n0 = blockIdx.x * 64;

  f32x4 acc[4] = {};

  // staging: per wave 16 rows of A and 16 rows of Bt (2 insts each)
  const int lrow = lane >> 3, slot = lane & 7;
  const int cswz = 8 * (slot ^ lrow);  // swizzled global col offset (r&7 == lrow)
  const ushort_t* ag = A  + (size_t)(m0 + wave * 16 + lrow) * K + cswz;
  const ushort_t* bg = Bt + (size_t)(n0 + wave * 16 + lrow) * K + cswz;
  ushort_t* la0 = &As[wave * 16][0];
  ushort_t* la1 = &As[wave * 16 + 8][0];
  ushort_t* lb0 = &Bs[wave * 16][0];
  ushort_t* lb1 = &Bs[wave * 16 + 8][0];

  // fragment-read swizzled column offsets
  const int swz = l15 & 7;

  for (int k0 = 0; k0 < K; k0 += 64) {
    __syncthreads();
    async16(ag + k0, la0);
    async16(ag + k0 + 8 * (size_t)K, la1);
    async16(bg + k0, lb0);
    async16(bg + k0 + 8 * (size_t)K, lb1);
    asm volatile("s_waitcnt vmcnt(0)" ::: "memory");
    __syncthreads();
#pragma unroll
    for (int s = 0; s < 2; s++) {
      const int acol = 8 * ((s * 4 + quad) ^ swz);
      bf16x8 af = *reinterpret_cast<const bf16x8*>(&As[wave * 16 + l15][acol]);
#pragma unroll
      for (int t = 0; t < 4; t++) {
        bf16x8 bfr = *reinterpret_cast<const bf16x8*>(&Bs[t * 16 + l15][acol]);
        acc[t] = MFMA16(af, bfr, acc[t]);
      }
    }
  }

#pragma unroll
  for (int t = 0; t < 4; t++) {
    const int col = n0 + t * 16 + l15;
    const float bv = bias[col];
#pragma unroll
    for (int rr = 0; rr < 4; rr++) {
      const int row = m0 + wave * 16 + quad * 4 + rr;
      const float v = acc[t][rr] + bv;
      if (F32OUT) reinterpret_cast<float*>(C)[(size_t)row * N + col] = v;
      else        reinterpret_cast<ushort_t*>(C)[(size_t)row * N + col] = f2bf(v);
    }
  }
}

// ---------------------------------------------------------------------------
// 3) Fused flash attention, split-K over k-blocks. QKV packed (row stride 1536:
//    Q at col h*64, K at 512+h*64, V at 1024+h*64).
// ---------------------------------------------------------------------------
__global__ __launch_bounds__(256) void attn_kernel(
    const ushort_t* __restrict__ QKV, const uint_t* __restrict__ DA,
    const float* __restrict__ wd, const float* __restrict__ wa,
    float* __restrict__ Opart, float* __restrict__ Mp, float* __restrict__ Lp) {
  const int qb = blockIdx.x, h = blockIdx.y;
  const int b = blockIdx.z / NSPLIT, split = blockIdx.z % NSPLIT;
  const int tid = threadIdx.x;
  const int wave = tid >> 6, lane = tid & 63;
  const int quad = lane >> 4, l15 = lane & 15;
  const int q0 = qb * 64;
  const float scale = 0.125f;
  const float wdh = wd[h], wah = wa[h];

  __shared__ ushort_t Ks[64][64];    // K tile, XOR-swizzled col blocks
  __shared__ ushort_t Vts[64][64];   // V^T tile, XOR-swizzled col blocks
  __shared__ ushort_t Ps[4][16][72];

  // Q fragments for this wave's 16-query stripe
  const int qrow = q0 + wave * 16 + l15;
  bf16x8 qf[2];
#pragma unroll
  for (int s = 0; s < 2; s++)
    qf[s] = *reinterpret_cast<const bf16x8*>(
        &QKV[(size_t)(b * SEQ + qrow) * NQKV + h * DK + s * 32 + quad * 8]);

  float m_run[4], l_run[4];
  f32x4 o[4] = {};
#pragma unroll
  for (int rr = 0; rr < 4; rr++) { m_run[rr] = -INFINITY; l_run[rr] = 0.f; }

  // K staging (async): per wave 16 rows, 2 insts
  const int lrow = lane >> 3, slot = lane & 7;
  const ushort_t* kg = QKV + (size_t)(b * SEQ + wave * 16 + lrow) * NQKV +
                       512 + h * DK + 8 * (slot ^ lrow);
  ushort_t* lk0 = &Ks[wave * 16][0];
  ushort_t* lk1 = &Ks[wave * 16 + 8][0];

  // V staging (manual transpose)
  const int sr = tid >> 3;       // 0..31
  const int sc = (tid & 7) * 8;  // 0..56
  const int c7 = tid & 7;
  const ushort_t* vg = QKV + (size_t)(b * SEQ + sr) * NQKV + 1024 + h * DK + sc;
  const int col0 = (sr & 7) + 8 * ((sr >> 3) ^ c7);
  const int col1 = (sr & 7) + 8 * (((sr >> 3) + 4) ^ c7);

  const int swz = l15 & 7;
  const uint_t* DArow = DA + (size_t)b * SEQ * SEQ;

  for (int kbi = 0; kbi < KB_PER; kbi++) {
    const int k0 = (split * KB_PER + kbi) * 64;
    __syncthreads();
    async16(kg + (size_t)k0 * NQKV, lk0);
    async16(kg + (size_t)(k0 + 8) * NQKV, lk1);
    bf16x8 v0 = *reinterpret_cast<const bf16x8*>(vg + (size_t)k0 * NQKV);
    bf16x8 v1 = *reinterpret_cast<const bf16x8*>(vg + (size_t)(k0 + 32) * NQKV);
#pragma unroll
    for (int j = 0; j < 8; j++) {
      Vts[sc + j][col0] = (ushort_t)v0[j];
      Vts[sc + j][col1] = (ushort_t)v1[j];
    }
    asm volatile("s_waitcnt vmcnt(0)" ::: "memory");
    __syncthreads();

    // issue bias loads early (overlap with QK^T MFMA)
    uint_t da[4][4];
#pragma unroll
    for (int t = 0; t < 4; t++) {
      const int kk = k0 + t * 16 + l15;
#pragma unroll
      for (int rr = 0; rr < 4; rr++) {
        const int qg = q0 + wave * 16 + quad * 4 + rr;
        da[t][rr] = DArow[(size_t)qg * SEQ + kk];
      }
    }

    // S = (Q K^T) * scale + wd*D + wa*A
    f32x4 sacc[4];
#pragma unroll
    for (int t = 0; t < 4; t++) {
      bf16x8 kf0 = *reinterpret_cast<const bf16x8*>(&Ks[t * 16 + l15][8 * (quad ^ swz)]);
      bf16x8 kf1 = *reinterpret_cast<const bf16x8*>(&Ks[t * 16 + l15][8 * ((4 + quad) ^ swz)]);
      f32x4 z = {};
      z = MFMA16(qf[0], kf0, z);
      sacc[t] = MFMA16(qf[1], kf1, z);
    }

    float sv[4][4];
    float mx[4] = {-INFINITY, -INFINITY, -INFINITY, -INFINITY};
#pragma unroll
    for (int t = 0; t < 4; t++) {
#pragma unroll
      for (int rr = 0; rr < 4; rr++) {
        const float fd = __builtin_bit_cast(float, da[t][rr] << 16);
        const float fa = __builtin_bit_cast(float, da[t][rr] & 0xFFFF0000u);
        float s = fmaf(wdh, fd, fmaf(wah, fa, sacc[t][rr] * scale));
        sv[t][rr] = s;
        mx[rr] = fmaxf(mx[rr], s);
      }
    }
#pragma unroll
    for (int rr = 0; rr < 4; rr++) {
      float m = mx[rr];
#pragma unroll
      for (int off = 1; off < 16; off <<= 1) m = fmaxf(m, __shfl_xor(m, off, 64));
      mx[rr] = m;
    }
    float alpha[4], rs[4];
#pragma unroll
    for (int rr = 0; rr < 4; rr++) {
      const float mn = fmaxf(m_run[rr], mx[rr]);
      alpha[rr] = __expf(m_run[rr] - mn);
      m_run[rr] = mn;
      rs[rr] = 0.f;
    }
#pragma unroll
    for (int t = 0; t < 4; t++) {
#pragma unroll
      for (int rr = 0; rr < 4; rr++) {
        const float p = __expf(sv[t][rr] - m_run[rr]);
        rs[rr] += p;
        Ps[wave][quad * 4 + rr][t * 16 + l15] = f2bf(p);
      }
    }
#pragma unroll
    for (int rr = 0; rr < 4; rr++) {
      float s = rs[rr];
#pragma unroll
      for (int off = 1; off < 16; off <<= 1) s += __shfl_xor(s, off, 64);
      l_run[rr] = l_run[rr] * alpha[rr] + s;
    }
#pragma unroll
    for (int dt = 0; dt < 4; dt++)
#pragma unroll
      for (int rr = 0; rr < 4; rr++) o[dt][rr] *= alpha[rr];

    // Ps is wave-private: wave-local LDS drain is enough (no barrier)
    asm volatile("s_waitcnt lgkmcnt(0)" ::: "memory");

    // O += P @ V
#pragma unroll
    for (int s2 = 0; s2 < 2; s2++) {
      bf16x8 pf = *reinterpret_cast<const bf16x8*>(&Ps[wave][l15][s2 * 32 + quad * 8]);
#pragma unroll
      for (int dt = 0; dt < 4; dt++) {
        const int vrow = dt * 16 + l15;
        const int vcb = (s2 * 4 + quad) ^ (vrow >> 3);
        bf16x8 vf = *reinterpret_cast<const bf16x8*>(&Vts[vrow][vcb * 8]);
        o[dt] = MFMA16(pf, vf, o[dt]);
      }
    }
  }

  // epilogue: write fp32 partials (un-normalized) + m, l
  const int pidx = (((b * NHEADS + h) * 32 + qb) * NSPLIT + split);
  float* op = Opart + (size_t)pidx * 4096;
#pragma unroll
  for (int dt = 0; dt < 4; dt++) {
#pragma unroll
    for (int rr = 0; rr < 4; rr++) {
      const int row = wave * 16 + quad * 4 + rr;
      op[row * 64 + dt * 16 + l15] = o[dt][rr];
    }
  }
  if (l15 == 0) {
#pragma unroll
    for (int rr = 0; rr < 4; rr++) {
      const int row = wave * 16 + quad * 4 + rr;
      Mp[(size_t)pidx * 64 + row] = m_run[rr];
      Lp[(size_t)pidx * 64 + row] = l_run[rr];
    }
  }
}

// ---------------------------------------------------------------------------
// 3b) split-K combine
// ---------------------------------------------------------------------------
__global__ __launch_bounds__(256) void combine_kernel(
    const float* __restrict__ Opart, const float* __restrict__ Mp,
    const float* __restrict__ Lp, ushort_t* __restrict__ AO) {
  const int qb = blockIdx.x, h = blockIdx.y, b = blockIdx.z;
  const int tid = threadIdx.x;
  const int lane = tid & 63, wq = tid >> 6;
  const int pidx0 = ((b * NHEADS + h) * 32 + qb) * NSPLIT;

  for (int r = 0; r < 16; r++) {
    const int q = wq * 16 + r;
    float m[NSPLIT], l[NSPLIT];
    float M = -INFINITY;
#pragma unroll
    for (int s = 0; s < NSPLIT; s++) {
      m[s] = Mp[(size_t)(pidx0 + s) * 64 + q];
      l[s] = Lp[(size_t)(pidx0 + s) * 64 + q];
      M = fmaxf(M, m[s]);
    }
    float L = 0.f, acc = 0.f;
#pragma unroll
    for (int s = 0; s < NSPLIT; s++) {
      const float w = __expf(m[s] - M);
      L += l[s] * w;
      acc += Opart[(size_t)(pidx0 + s) * 4096 + q * 64 + lane] * w;
    }
    const int row = b * SEQ + qb * 64 + q;
    AO[(size_t)row * DMODEL + h * DK + lane] = f2bf(acc / L);
  }
}

// ---------------------------------------------------------------------------
extern "C" void kernel_launch(void* const* d_in, const int* in_sizes, int n_in,
                              void* d_out, int out_size, void* d_ws, size_t ws_size,
                              hipStream_t stream) {
  const float* x  = (const float*)d_in[0];
  const float* Dm = (const float*)d_in[1];
  const float* Am = (const float*)d_in[2];
  const float* Wq = (const float*)d_in[3];
  const float* bq = (const float*)d_in[4];
  const float* Wk = (const float*)d_in[5];
  const float* bk = (const float*)d_in[6];
  const float* Wv = (const float*)d_in[7];
  const float* bv = (const float*)d_in[8];
  const float* Wo = (const float*)d_in[9];
  const float* bo = (const float*)d_in[10];
  const float* wd = (const float*)d_in[11];
  const float* wa = (const float*)d_in[12];

  char* ws = (char*)d_ws;
  size_t off = 0;
  ushort_t* xb    = (ushort_t*)(ws + off); off += (size_t)XE * 2;         // 4 MB
  ushort_t* wqkvb = (ushort_t*)(ws + off); off += (size_t)3 * WE * 2;     // 1.5 MB
  ushort_t* wob   = (ushort_t*)(ws + off); off += (size_t)WE * 2;         // 0.5 MB
  ushort_t* QKVb  = (ushort_t*)(ws + off); off += (size_t)MROWS * NQKV * 2; // 12 MB
  ushort_t* AO    = (ushort_t*)(ws + off); off += (size_t)XE * 2;         // 4 MB
  float*    bqkv  = (float*)(ws + off);    off += (size_t)NQKV * 4;       // 6 KB
  off = (off + 255) & ~(size_t)255;
  uint_t*   DAb   = (uint_t*)(ws + off);   off += (size_t)BATCH * SEQ * SEQ * 4; // 33.5 MB
  float*    Opart = (float*)(ws + off);    off += (size_t)512 * NSPLIT * 4096 * 4; // 33.5 MB
  float*    Mpart = (float*)(ws + off);    off += (size_t)512 * NSPLIT * 64 * 4;
  float*    Lpart = (float*)(ws + off);

  // 1) convert inputs to bf16 (+bias concat); pack D/A
  const int conv_blocks = (XE + 4 * WE) / 1024;
  convert_kernel<<<conv_blocks + 1, 256, 0, stream>>>(
      x, Wq, Wk, Wv, Wo, bq, bk, bv, xb, bqkv);
  pack_da_kernel<<<(BATCH * SEQ * SEQ) / 1024, 256, 0, stream>>>(Dm, Am, DAb);

  // 2) fused QKV projection: (4096 x 512) @ (1536 x 512)^T
  dim3 qkvgrid(NQKV / 64, MROWS / 64);
  gemm_bt<false><<<qkvgrid, 256, 0, stream>>>(xb, wqkvb, bqkv, QKVb, NQKV, DMODEL);

  // 3) fused attention (split-K) + combine
  dim3 agrid(SEQ / 64, NHEADS, BATCH * NSPLIT);
  attn_kernel<<<agrid, 256, 0, stream>>>(QKVb, DAb, wd, wa, Opart, Mpart, Lpart);
  dim3 cgrid(SEQ / 64, NHEADS, BATCH);
  combine_kernel<<<cgrid, 256, 0, stream>>>(Opart, Mpart, Lpart, AO);

  // 4) output projection (fp32 out)
  dim3 ogrid(DMODEL / 64, MROWS / 64);
  gemm_bt<true><<<ogrid, 256, 0, stream>>>(AO, wob, bo, (float*)d_out, DMODEL, DMODEL);
}